// Round 9
// baseline (390.766 us; speedup 1.0000x reference)
//
#include <hip/hip_runtime.h>
#include <math.h>

typedef unsigned int uint;
typedef unsigned short ushort;
typedef unsigned long long u64;
typedef __attribute__((ext_vector_type(8))) short short8;
typedef __attribute__((ext_vector_type(4))) float f32x4;

// Problem: z (16,256,32,32) fp32, emb (8192,256) fp32. N=16384 rows, K=256, C=8192 codes.
// out (fp32): [0,4194304) z_q (b,c,h,w) | [4194304] loss | [4194305,+16384) idx as float
//
// Pipeline: bf16-MFMA screen (codebook LDS-resident, barrier-free K-loop, 8 waves/block)
// -> per-row per-8code-group max, 2 groups packed bf16 in u32 (gmax[n][512]) ->
// wave-per-row select within margin of global max -> exact fp32 rescore
// (validated sequential-k numerics, d = fl32(sumz - 2*dot)) -> u64 (score|idx)
// min, lowest-index ties. Margin covers 2*eps_screen + bf16 store rounding.
//
// ws: zt fp32[16384][256] @0 | zpk 8MB | epk 4MB | sumz | gmax u32[16384][512] | best | loss,ctr
#define WS_ZT   0ull
#define WS_ZPK  16777216ull
#define WS_EPK  25165824ull
#define WS_SUMZ 29360128ull
#define WS_GMAX 29425664ull
#define WS_BEST 62980096ull
#define WS_LOSS 63111168ull

#define DOT_MARGIN 1.2e-4f  // bound: 2*eps_screen(2.6e-5) + bf16 store ulp(1.5e-5) ~ 4.1e-5; 3x safety

__device__ __forceinline__ ushort f2bf(float f) {           // RNE fp32->bf16
  uint b = __float_as_uint(f);
  b += 0x7fffu + ((b >> 16) & 1u);
  return (ushort)(b >> 16);
}
__device__ __forceinline__ uint ford(float f) {             // orderable uint
  uint b = __float_as_uint(f);
  return (b & 0x80000000u) ? ~b : (b | 0x80000000u);
}
__device__ __forceinline__ void gload_lds16(const void* g, void* l) {
  __builtin_amdgcn_global_load_lds(
      (const __attribute__((address_space(1))) unsigned int*)g,
      (__attribute__((address_space(3))) unsigned int*)l, 16, 0, 0);
}

// ---------------- prep: zt[n][k] fp32 + zpk fragment-packed bf16 (validated)
__global__ __launch_bounds__(256) void prep_z(const float* __restrict__ z,
                                              float* __restrict__ zt,
                                              ushort* __restrict__ zpk) {
  __shared__ float tile[64][65];
  const int bid = blockIdx.x;
  const int kt = bid & 3, hwt = (bid >> 2) & 15, b = bid >> 6;
  const int t = threadIdx.x, lane = t & 63, grp = t >> 6;
  const float* src = z + b * 262144 + (kt * 64) * 1024 + hwt * 64;
  for (int kk = grp; kk < 64; kk += 4)
    tile[kk][lane] = src[kk * 1024 + lane];                 // coalesced over hw
  __syncthreads();
  for (int rr = grp; rr < 64; rr += 4) {                    // zt: coalesced over k
    const int n = b * 1024 + hwt * 64 + rr;
    zt[n * 256 + kt * 64 + lane] = tile[lane][rr];
  }
  for (int u = t; u < 512; u += 256) {                      // zpk: 16B frag pieces
    const int n_loc = u & 63, kg = u >> 6;
    const int n = b * 1024 + hwt * 64 + n_loc;
    const int k0 = kt * 64 + kg * 8;
    short8 s;
#pragma unroll
    for (int j = 0; j < 8; ++j) s[j] = (short)f2bf(tile[kg * 8 + j][n_loc]);
    *(short8*)(zpk + (size_t)(n >> 4) * 4096 + (k0 >> 5) * 512 +
               ((k0 >> 3) & 3) * 128 + (n & 15) * 8) = s;
  }
}

// ---------------- prep: epk fragment-packed bf16 codebook (validated)
__global__ __launch_bounds__(256) void prep_e(const float* __restrict__ emb,
                                              ushort* __restrict__ epk) {
  const int u = blockIdx.x * 256 + threadIdx.x;             // 262144 threads
  const int c = u >> 5, k0 = (u & 31) * 8;
  const float4 v0 = *(const float4*)(emb + c * 256 + k0);
  const float4 v1 = *(const float4*)(emb + c * 256 + k0 + 4);
  short8 s;
  s[0] = (short)f2bf(v0.x); s[1] = (short)f2bf(v0.y);
  s[2] = (short)f2bf(v0.z); s[3] = (short)f2bf(v0.w);
  s[4] = (short)f2bf(v1.x); s[5] = (short)f2bf(v1.y);
  s[6] = (short)f2bf(v1.z); s[7] = (short)f2bf(v1.w);
  *(short8*)(epk + (size_t)(c >> 4) * 4096 + (k0 >> 5) * 512 +
             ((k0 >> 3) & 3) * 128 + (c & 15) * 8) = s;
}

// ---------------- sumz[n] = ||z_n||^2, sequential-k fp32 (validated numerics)
__global__ __launch_bounds__(256) void zsum_kernel(const float* __restrict__ z,
                                                   float* __restrict__ sumz) {
  const int n = (blockIdx.x << 8) + threadIdx.x;
  const int b = n >> 10, hw = n & 1023;
  const float* zb = z + b * 262144 + hw;
  float s = 0.f;
#pragma unroll 8
  for (int c = 0; c < 256; ++c) { const float v = zb[c << 10]; s += v * v; }
  sumz[n] = s;
}

// ---------------- screening GEMM: codebook panel LDS-resident, barrier-free K-loop
// 512 threads / 8 waves per block: wave = (a = w&1 code-half, rh = w>>1 row-quarter).
// Block: 1024 rows x 128 codes, 4 strips of 256 rows; per wave-strip: 64 rows x 64 codes.
// k32-granular rotating prefetch (zc[4]/zn[4]); 16 waves/CU = 4 waves/SIMD.
__global__ __launch_bounds__(512, 4) void gemm_screen(const ushort* __restrict__ zpk,
                                                      const ushort* __restrict__ epk,
                                                      uint* __restrict__ gmax) {
  __shared__ ushort Cs[32768];   // 64 KB: 64 frags x 1KB, frag f = c16loc*8 + k32
  const int t = threadIdx.x;
  const int w = t >> 6, lane = t & 63;
  const int bid = blockIdx.x;
  const int x = bid & 7, y = bid >> 3;
  const int p = y & 7, rowg = y >> 3;
  const int colb = p * 8 + x;              // XCD x keeps its 8 epk panels L2-resident
  const int n0 = rowg << 10;
  const int a = w & 1, rh = w >> 1;        // code-half, row-quarter
  const int m16 = lane & 15, q = lane >> 4;

  // stage code panel once: 8 coalesced 1KB DMAs per wave
#pragma unroll
  for (int f2 = 0; f2 < 8; ++f2) {
    const int f = w * 8 + f2;
    gload_lds16(epk + (size_t)colb * 32768 + f * 512 + lane * 8, (char*)Cs + f * 1024);
  }
  __syncthreads();                         // only barrier in the kernel

  short8 zc[4], zn[4];                     // z frags, k32-granular rotation
  const ushort* zb0 = zpk + ((size_t)(n0 >> 4) + rh * 4) * 4096 + lane * 8;
#pragma unroll
  for (int jr = 0; jr < 4; ++jr) zc[jr] = *(const short8*)(zb0 + jr * 4096);

  for (int strip = 0; strip < 4; ++strip) {
    const int rbase = n0 + strip * 256 + rh * 64;
    const ushort* zb = zpk + (size_t)(rbase >> 4) * 4096 + lane * 8;
    f32x4 acc[4][4];                       // [ic][jr]
#pragma unroll
    for (int i = 0; i < 4; ++i)
#pragma unroll
      for (int j = 0; j < 4; ++j) acc[i][j] = {0.f, 0.f, 0.f, 0.f};

#pragma unroll
    for (int s32 = 0; s32 < 8; ++s32) {    // k32 steps over K=256
      if (s32 < 7) {
#pragma unroll
        for (int jr = 0; jr < 4; ++jr)
          zn[jr] = *(const short8*)(zb + jr * 4096 + (s32 + 1) * 512);
      }
      short8 cv[4];
#pragma unroll
      for (int ic = 0; ic < 4; ++ic)
        cv[ic] = *(const short8*)&Cs[(size_t)((a * 4 + ic) * 8 + s32) * 512 + lane * 8];
#pragma unroll
      for (int ic = 0; ic < 4; ++ic)
#pragma unroll
        for (int jr = 0; jr < 4; ++jr)
          acc[ic][jr] = __builtin_amdgcn_mfma_f32_16x16x32_bf16(cv[ic], zc[jr],
                                                                acc[ic][jr], 0, 0, 0);
#pragma unroll
      for (int jr = 0; jr < 4; ++jr) zc[jr] = zn[jr];
    }

    // prefetch next strip's first k32 BEFORE the epilogue
    if (strip < 3) {
      const ushort* zbn = zpk + (size_t)((rbase + 256) >> 4) * 4096 + lane * 8;
#pragma unroll
      for (int jr = 0; jr < 4; ++jr) zc[jr] = *(const short8*)(zbn + jr * 4096);
    }

    // epilogue: D row=code(q*4+reg), col=z-row(m16). 8-group g0 = q{0,1} regs,
    // g1 = q{2,3}. in-lane reg-max -> xor16 (8-max) -> xor32 (swap halves) -> pack.
#pragma unroll
    for (int jr = 0; jr < 4; ++jr) {
      uint pk[4];
#pragma unroll
      for (int ic = 0; ic < 4; ++ic) {
        float m = fmaxf(fmaxf(acc[ic][jr][0], acc[ic][jr][1]),
                        fmaxf(acc[ic][jr][2], acc[ic][jr][3]));
        m = fmaxf(m, __shfl_xor(m, 16, 64));     // 8-group max (own half)
        const float o = __shfl_xor(m, 32, 64);   // other half's 8-group max
        const float glo = (q & 2) ? o : m;
        const float ghi = (q & 2) ? m : o;
        pk[ic] = (uint)f2bf(glo) | ((uint)f2bf(ghi) << 16);
      }
      const uint sv = (q == 0) ? pk[0] : (q == 1) ? pk[1] : (q == 2) ? pk[2] : pk[3];
      gmax[(size_t)(rbase + jr * 16 + m16) * 512 + colb * 8 + a * 4 + q] = sv;
    }
  }
}

// ---------------- wave-per-row: global max over 1024 8-groups -> exact rescore of hits
__global__ __launch_bounds__(256) void select_rescore(const uint* __restrict__ gmax,
                                                      const float* __restrict__ zt,
                                                      const float* __restrict__ emb,
                                                      const float* __restrict__ sumz,
                                                      u64* __restrict__ best) {
  const int t = threadIdx.x, w = t >> 6, lane = t & 63;
  const int n = (blockIdx.x << 2) + w;     // one wave per row, no __syncthreads
  __shared__ float zrow[4][256];
  __shared__ ushort hits[4][64];
  __shared__ int nh[4];
  if (lane == 0) nh[w] = 0;
  ((float4*)zrow[w])[lane] = ((const float4*)(zt + (size_t)n * 256))[lane];
  const uint4 r0 = ((const uint4*)(gmax + (size_t)n * 512))[lane];        // u32 4l..
  const uint4 r1 = ((const uint4*)(gmax + (size_t)n * 512))[lane + 64];   // 256+4l..
  const uint uv[8] = {r0.x, r0.y, r0.z, r0.w, r1.x, r1.y, r1.z, r1.w};
  float m = -INFINITY;
#pragma unroll
  for (int j = 0; j < 8; ++j) {
    m = fmaxf(m, __uint_as_float(uv[j] << 16));
    m = fmaxf(m, __uint_as_float(uv[j] & 0xffff0000u));
  }
#pragma unroll
  for (int off = 1; off < 64; off <<= 1) m = fmaxf(m, __shfl_xor(m, off, 64));
  const float thr = m - DOT_MARGIN;
#pragma unroll
  for (int j = 0; j < 8; ++j) {
    const int ui = (j < 4) ? lane * 4 + j : 256 + lane * 4 + (j - 4);
    if (__uint_as_float(uv[j] << 16) >= thr) {
      const int p = atomicAdd(&nh[w], 1);
      if (p < 64) hits[w][p] = (ushort)(ui * 2);
    }
    if (__uint_as_float(uv[j] & 0xffff0000u) >= thr) {
      const int p = atomicAdd(&nh[w], 1);
      if (p < 64) hits[w][p] = (ushort)(ui * 2 + 1);
    }
  }
  __threadfence_block();
  int K = nh[w]; if (K > 64) K = 64;
  const float sz = sumz[n];
  u64 bk = ~0ull;
  for (int id = lane; id < K * 8; id += 64) {
    const int gid = hits[w][id >> 3];
    const int u = gid >> 1, h = gid & 1;
    const int c = (u >> 3) * 128 + (u & 7) * 16 + h * 8 + (id & 7);
    const float4* ea = (const float4*)(emb + c * 256);
    const float4* za = (const float4*)zrow[w];
    float sdot = 0.f;
#pragma unroll 8
    for (int k = 0; k < 64; ++k) {          // validated sequential-k fp32 numerics
      const float4 a = za[k], e = ea[k];
      sdot = fmaf(a.x, e.x, sdot); sdot = fmaf(a.y, e.y, sdot);
      sdot = fmaf(a.z, e.z, sdot); sdot = fmaf(a.w, e.w, sdot);
    }
    const float d = sz - 2.f * sdot;
    const u64 key = ((u64)ford(d) << 32) | (uint)c;
    if (key < bk) bk = key;
  }
#pragma unroll
  for (int off = 1; off < 64; off <<= 1) {
    const u64 o = (((u64)(uint)__shfl_xor((int)(bk >> 32), off, 64)) << 32) |
                  (uint)__shfl_xor((int)(bk & 0xffffffffu), off, 64);
    if (o < bk) bk = o;
  }
  if (lane == 0) best[n] = bk;              // single owner, plain store
}

// ---------------- gather z_q, idx, loss + fused finalize (done-counter)
__global__ __launch_bounds__(256) void gather_kernel(const float* __restrict__ z,
                                                     const float* __restrict__ emb,
                                                     const u64* __restrict__ best,
                                                     float* __restrict__ out,
                                                     double* __restrict__ loss_acc,
                                                     uint* __restrict__ done) {
  const int t = threadIdx.x;
  const int n0 = blockIdx.x << 6;
  const int n = n0 + (t & 63);
  const int idx = (int)(best[n] & 0xffffffffull);
  const int b_i = n >> 10, hw = n & 1023;
  const int c0 = t >> 6;
  const float* zb = z + b_i * 262144 + hw;
  float* ob = out + b_i * 262144 + hw;
  const float* eb = emb + idx * 256;
  float lsum = 0.f;
#pragma unroll 4
  for (int c = c0; c < 256; c += 4) {
    const float ev = eb[c];
    const float zv = zb[c << 10];
    ob[c << 10] = ev;
    const float d = ev - zv;
    lsum += d * d;
  }
  if (c0 == 0) out[4194305 + n] = (float)idx;
#pragma unroll
  for (int off = 32; off; off >>= 1) lsum += __shfl_down(lsum, off, 64);
  __shared__ double wsum[4];
  if ((t & 63) == 0) wsum[t >> 6] = (double)lsum;
  __syncthreads();
  if (t == 0) {
    atomicAdd(loss_acc, wsum[0] + wsum[1] + wsum[2] + wsum[3]);
    __threadfence();
    if (atomicAdd(done, 1u) == 255u) {       // last of 256 blocks
      __threadfence();
      out[4194304] = (float)(1.25 * (*(volatile double*)loss_acc) / 4194304.0);
    }
  }
}

// ---------------- launch
extern "C" void kernel_launch(void* const* d_in, const int* in_sizes, int n_in,
                              void* d_out, int out_size, void* d_ws, size_t ws_size,
                              hipStream_t stream) {
  const float* z = (const float*)d_in[0];
  const float* emb = (const float*)d_in[1];
  float* out = (float*)d_out;
  char* ws = (char*)d_ws;
  float* zt = (float*)(ws + WS_ZT);
  ushort* zpk = (ushort*)(ws + WS_ZPK);
  ushort* epk = (ushort*)(ws + WS_EPK);
  float* sumz = (float*)(ws + WS_SUMZ);
  uint* gmax = (uint*)(ws + WS_GMAX);
  u64* best = (u64*)(ws + WS_BEST);
  double* loss_acc = (double*)(ws + WS_LOSS);
  uint* done = (uint*)(ws + WS_LOSS + 8);

  hipMemsetAsync(ws + WS_LOSS, 0, 16, stream);   // loss_acc + done ctr
  prep_z<<<1024, 256, 0, stream>>>(z, zt, zpk);
  prep_e<<<1024, 256, 0, stream>>>(emb, epk);
  zsum_kernel<<<64, 256, 0, stream>>>(z, sumz);
  gemm_screen<<<1024, 512, 0, stream>>>(zpk, epk, gmax);
  select_rescore<<<4096, 256, 0, stream>>>(gmax, zt, emb, sumz, best);
  gather_kernel<<<256, 256, 0, stream>>>(z, emb, best, out, loss_acc, done);
}

// Round 10
// 284.247 us; speedup vs baseline: 1.3747x; 1.3747x over previous
//
#include <hip/hip_runtime.h>
#include <math.h>

typedef unsigned int uint;
typedef unsigned short ushort;
typedef unsigned long long u64;
typedef __attribute__((ext_vector_type(8))) short short8;
typedef __attribute__((ext_vector_type(4))) float f32x4;

// Problem: z (16,256,32,32) fp32, emb (8192,256) fp32. N=16384 rows, K=256, C=8192 codes.
// out (fp32): [0,4194304) z_q (b,c,h,w) | [4194304] loss | [4194305,+16384) idx as float
//
// Pipeline: bf16-MFMA screen (codebook 64-code/32KB panel LDS-resident, barrier-free
// K-loop, 3 blocks/CU) -> per-row per-8code-group max, 2 groups packed bf16 in u32
// (gmax[n][512]) -> wave-per-row select within margin of global max -> exact fp32
// rescore (validated sequential-k numerics, d = fl32(sumz - 2*dot)) -> u64
// (score|idx) min, lowest-index ties.
//
// HW lesson (round 9): __launch_bounds__ 2nd arg acted as CUDA min-BLOCKS/CU here
// ((512,4) -> 64 VGPR -> acc spilled -> 525MB scratch FETCH). Never cap below live set.
//
// ws: zt fp32[16384][256] @0 | zpk 8MB | epk 4MB | sumz | gmax u32[16384][512] | best | loss,ctr
#define WS_ZT   0ull
#define WS_ZPK  16777216ull
#define WS_EPK  25165824ull
#define WS_SUMZ 29360128ull
#define WS_GMAX 29425664ull
#define WS_BEST 62980096ull
#define WS_LOSS 63111168ull

#define DOT_MARGIN 1.2e-4f  // validated r9: 2*eps_screen + bf16 store ulp ~4.1e-5; 3x safety

__device__ __forceinline__ ushort f2bf(float f) {           // RNE fp32->bf16
  uint b = __float_as_uint(f);
  b += 0x7fffu + ((b >> 16) & 1u);
  return (ushort)(b >> 16);
}
__device__ __forceinline__ uint ford(float f) {             // orderable uint
  uint b = __float_as_uint(f);
  return (b & 0x80000000u) ? ~b : (b | 0x80000000u);
}
__device__ __forceinline__ void gload_lds16(const void* g, void* l) {
  __builtin_amdgcn_global_load_lds(
      (const __attribute__((address_space(1))) unsigned int*)g,
      (__attribute__((address_space(3))) unsigned int*)l, 16, 0, 0);
}

// ---------------- prep: zt[n][k] fp32 + zpk fragment-packed bf16 (validated)
__global__ __launch_bounds__(256) void prep_z(const float* __restrict__ z,
                                              float* __restrict__ zt,
                                              ushort* __restrict__ zpk) {
  __shared__ float tile[64][65];
  const int bid = blockIdx.x;
  const int kt = bid & 3, hwt = (bid >> 2) & 15, b = bid >> 6;
  const int t = threadIdx.x, lane = t & 63, grp = t >> 6;
  const float* src = z + b * 262144 + (kt * 64) * 1024 + hwt * 64;
  for (int kk = grp; kk < 64; kk += 4)
    tile[kk][lane] = src[kk * 1024 + lane];                 // coalesced over hw
  __syncthreads();
  for (int rr = grp; rr < 64; rr += 4) {                    // zt: coalesced over k
    const int n = b * 1024 + hwt * 64 + rr;
    zt[n * 256 + kt * 64 + lane] = tile[lane][rr];
  }
  for (int u = t; u < 512; u += 256) {                      // zpk: 16B frag pieces
    const int n_loc = u & 63, kg = u >> 6;
    const int n = b * 1024 + hwt * 64 + n_loc;
    const int k0 = kt * 64 + kg * 8;
    short8 s;
#pragma unroll
    for (int j = 0; j < 8; ++j) s[j] = (short)f2bf(tile[kg * 8 + j][n_loc]);
    *(short8*)(zpk + (size_t)(n >> 4) * 4096 + (k0 >> 5) * 512 +
               ((k0 >> 3) & 3) * 128 + (n & 15) * 8) = s;
  }
}

// ---------------- prep: epk fragment-packed bf16 codebook (validated)
__global__ __launch_bounds__(256) void prep_e(const float* __restrict__ emb,
                                              ushort* __restrict__ epk) {
  const int u = blockIdx.x * 256 + threadIdx.x;             // 262144 threads
  const int c = u >> 5, k0 = (u & 31) * 8;
  const float4 v0 = *(const float4*)(emb + c * 256 + k0);
  const float4 v1 = *(const float4*)(emb + c * 256 + k0 + 4);
  short8 s;
  s[0] = (short)f2bf(v0.x); s[1] = (short)f2bf(v0.y);
  s[2] = (short)f2bf(v0.z); s[3] = (short)f2bf(v0.w);
  s[4] = (short)f2bf(v1.x); s[5] = (short)f2bf(v1.y);
  s[6] = (short)f2bf(v1.z); s[7] = (short)f2bf(v1.w);
  *(short8*)(epk + (size_t)(c >> 4) * 4096 + (k0 >> 5) * 512 +
             ((k0 >> 3) & 3) * 128 + (c & 15) * 8) = s;
}

// ---------------- sumz[n] = ||z_n||^2, sequential-k fp32 (validated numerics)
__global__ __launch_bounds__(256) void zsum_kernel(const float* __restrict__ z,
                                                   float* __restrict__ sumz) {
  const int n = (blockIdx.x << 8) + threadIdx.x;
  const int b = n >> 10, hw = n & 1023;
  const float* zb = z + b * 262144 + hw;
  float s = 0.f;
#pragma unroll 8
  for (int c = 0; c < 256; ++c) { const float v = zb[c << 10]; s += v * v; }
  sumz[n] = s;
}

// ---------------- screening GEMM: 64-code (32 KB) panel LDS-resident, barrier-free
// 256 threads / 4 waves; all waves share the 4 code-tiles, wave w owns row-quarter w.
// Block: 1024 rows x 64 codes, 4 strips of 256 rows; per wave-strip 64 rows x 64 codes.
// grid 2048 = 8 XCD x 16 colb x 16 rowg; VGPR ~140 -> 3 blocks/CU = 12 waves/CU.
__global__ __launch_bounds__(256) void gemm_screen(const ushort* __restrict__ zpk,
                                                   const ushort* __restrict__ epk,
                                                   uint* __restrict__ gmax) {
  __shared__ ushort Cs[16384];   // 32 KB: 32 frags x 1KB, frag f = c16loc*8 + k32
  const int t = threadIdx.x;
  const int w = t >> 6, lane = t & 63;
  const int bid = blockIdx.x;
  const int x = bid & 7, y = bid >> 3;
  const int colb = (y & 15) * 8 + x;       // 0..127; XCD x owns 16 panels (512KB, L2)
  const int rowg = y >> 4;                 // 0..15
  const int n0 = rowg << 10;
  const int m16 = lane & 15, q = lane >> 4;

  // stage code panel once: 8 coalesced 1KB DMAs per wave
#pragma unroll
  for (int f2 = 0; f2 < 8; ++f2) {
    const int f = w * 8 + f2;
    gload_lds16(epk + (size_t)colb * 16384 + f * 512 + lane * 8, (char*)Cs + f * 1024);
  }
  __syncthreads();                         // only barrier in the kernel

  short8 zc[4], zn[4];                     // z frags, k32-granular rotation
  const ushort* zb0 = zpk + ((size_t)(n0 >> 4) + w * 4) * 4096 + lane * 8;
#pragma unroll
  for (int jr = 0; jr < 4; ++jr) zc[jr] = *(const short8*)(zb0 + jr * 4096);

  for (int strip = 0; strip < 4; ++strip) {
    const int rbase = n0 + strip * 256 + w * 64;
    const ushort* zb = zpk + (size_t)(rbase >> 4) * 4096 + lane * 8;
    f32x4 acc[4][4];                       // [ic][jr]
#pragma unroll
    for (int i = 0; i < 4; ++i)
#pragma unroll
      for (int j = 0; j < 4; ++j) acc[i][j] = {0.f, 0.f, 0.f, 0.f};

#pragma unroll
    for (int s32 = 0; s32 < 8; ++s32) {    // k32 steps over K=256
      if (s32 < 7) {
#pragma unroll
        for (int jr = 0; jr < 4; ++jr)
          zn[jr] = *(const short8*)(zb + jr * 4096 + (s32 + 1) * 512);
      }
      short8 cv[4];
#pragma unroll
      for (int ic = 0; ic < 4; ++ic)
        cv[ic] = *(const short8*)&Cs[(size_t)(ic * 8 + s32) * 512 + lane * 8];
#pragma unroll
      for (int ic = 0; ic < 4; ++ic)
#pragma unroll
        for (int jr = 0; jr < 4; ++jr)
          acc[ic][jr] = __builtin_amdgcn_mfma_f32_16x16x32_bf16(cv[ic], zc[jr],
                                                                acc[ic][jr], 0, 0, 0);
#pragma unroll
      for (int jr = 0; jr < 4; ++jr) zc[jr] = zn[jr];
    }

    // prefetch next strip's first k32 BEFORE the epilogue
    if (strip < 3) {
      const ushort* zbn = zpk + (size_t)((rbase + 256) >> 4) * 4096 + lane * 8;
#pragma unroll
      for (int jr = 0; jr < 4; ++jr) zc[jr] = *(const short8*)(zbn + jr * 4096);
    }

    // epilogue: D row=code(q*4+reg), col=z-row(m16). 8-group g0 = q{0,1} regs,
    // g1 = q{2,3}. in-lane reg-max -> xor16 (8-max) -> xor32 (swap halves) -> pack.
#pragma unroll
    for (int jr = 0; jr < 4; ++jr) {
      uint pk[4];
#pragma unroll
      for (int ic = 0; ic < 4; ++ic) {
        float m = fmaxf(fmaxf(acc[ic][jr][0], acc[ic][jr][1]),
                        fmaxf(acc[ic][jr][2], acc[ic][jr][3]));
        m = fmaxf(m, __shfl_xor(m, 16, 64));     // 8-group max (own half)
        const float o = __shfl_xor(m, 32, 64);   // other half's 8-group max
        const float glo = (q & 2) ? o : m;
        const float ghi = (q & 2) ? m : o;
        pk[ic] = (uint)f2bf(glo) | ((uint)f2bf(ghi) << 16);
      }
      const uint sv = (q == 0) ? pk[0] : (q == 1) ? pk[1] : (q == 2) ? pk[2] : pk[3];
      gmax[(size_t)(rbase + jr * 16 + m16) * 512 + colb * 4 + q] = sv;
    }
  }
}

// ---------------- wave-per-row: global max over 1024 8-groups -> exact rescore of hits
__global__ __launch_bounds__(256) void select_rescore(const uint* __restrict__ gmax,
                                                      const float* __restrict__ zt,
                                                      const float* __restrict__ emb,
                                                      const float* __restrict__ sumz,
                                                      u64* __restrict__ best) {
  const int t = threadIdx.x, w = t >> 6, lane = t & 63;
  const int n = (blockIdx.x << 2) + w;     // one wave per row, no __syncthreads
  __shared__ float zrow[4][256];
  __shared__ ushort hits[4][64];
  __shared__ int nh[4];
  if (lane == 0) nh[w] = 0;
  ((float4*)zrow[w])[lane] = ((const float4*)(zt + (size_t)n * 256))[lane];
  const uint4 r0 = ((const uint4*)(gmax + (size_t)n * 512))[lane];        // u32 4l..
  const uint4 r1 = ((const uint4*)(gmax + (size_t)n * 512))[lane + 64];   // 256+4l..
  const uint uv[8] = {r0.x, r0.y, r0.z, r0.w, r1.x, r1.y, r1.z, r1.w};
  float m = -INFINITY;
#pragma unroll
  for (int j = 0; j < 8; ++j) {
    m = fmaxf(m, __uint_as_float(uv[j] << 16));
    m = fmaxf(m, __uint_as_float(uv[j] & 0xffff0000u));
  }
#pragma unroll
  for (int off = 1; off < 64; off <<= 1) m = fmaxf(m, __shfl_xor(m, off, 64));
  const float thr = m - DOT_MARGIN;
#pragma unroll
  for (int j = 0; j < 8; ++j) {
    const int ui = (j < 4) ? lane * 4 + j : 256 + lane * 4 + (j - 4);
    if (__uint_as_float(uv[j] << 16) >= thr) {
      const int p = atomicAdd(&nh[w], 1);
      if (p < 64) hits[w][p] = (ushort)(ui * 2);
    }
    if (__uint_as_float(uv[j] & 0xffff0000u) >= thr) {
      const int p = atomicAdd(&nh[w], 1);
      if (p < 64) hits[w][p] = (ushort)(ui * 2 + 1);
    }
  }
  __threadfence_block();
  int K = nh[w]; if (K > 64) K = 64;
  const float sz = sumz[n];
  u64 bk = ~0ull;
  for (int id = lane; id < K * 8; id += 64) {
    const int gid = hits[w][id >> 3];
    const int u = gid >> 1, h = gid & 1;
    const int c = (u >> 3) * 128 + (u & 7) * 16 + h * 8 + (id & 7);
    const float4* ea = (const float4*)(emb + c * 256);
    const float4* za = (const float4*)zrow[w];
    float sdot = 0.f;
#pragma unroll 8
    for (int k = 0; k < 64; ++k) {          // validated sequential-k fp32 numerics
      const float4 a = za[k], e = ea[k];
      sdot = fmaf(a.x, e.x, sdot); sdot = fmaf(a.y, e.y, sdot);
      sdot = fmaf(a.z, e.z, sdot); sdot = fmaf(a.w, e.w, sdot);
    }
    const float d = sz - 2.f * sdot;
    const u64 key = ((u64)ford(d) << 32) | (uint)c;
    if (key < bk) bk = key;
  }
#pragma unroll
  for (int off = 1; off < 64; off <<= 1) {
    const u64 o = (((u64)(uint)__shfl_xor((int)(bk >> 32), off, 64)) << 32) |
                  (uint)__shfl_xor((int)(bk & 0xffffffffu), off, 64);
    if (o < bk) bk = o;
  }
  if (lane == 0) best[n] = bk;              // single owner, plain store
}

// ---------------- gather z_q, idx, loss + fused finalize (done-counter)
__global__ __launch_bounds__(256) void gather_kernel(const float* __restrict__ z,
                                                     const float* __restrict__ emb,
                                                     const u64* __restrict__ best,
                                                     float* __restrict__ out,
                                                     double* __restrict__ loss_acc,
                                                     uint* __restrict__ done) {
  const int t = threadIdx.x;
  const int n0 = blockIdx.x << 6;
  const int n = n0 + (t & 63);
  const int idx = (int)(best[n] & 0xffffffffull);
  const int b_i = n >> 10, hw = n & 1023;
  const int c0 = t >> 6;
  const float* zb = z + b_i * 262144 + hw;
  float* ob = out + b_i * 262144 + hw;
  const float* eb = emb + idx * 256;
  float lsum = 0.f;
#pragma unroll 4
  for (int c = c0; c < 256; c += 4) {
    const float ev = eb[c];
    const float zv = zb[c << 10];
    ob[c << 10] = ev;
    const float d = ev - zv;
    lsum += d * d;
  }
  if (c0 == 0) out[4194305 + n] = (float)idx;
#pragma unroll
  for (int off = 32; off; off >>= 1) lsum += __shfl_down(lsum, off, 64);
  __shared__ double wsum[4];
  if ((t & 63) == 0) wsum[t >> 6] = (double)lsum;
  __syncthreads();
  if (t == 0) {
    atomicAdd(loss_acc, wsum[0] + wsum[1] + wsum[2] + wsum[3]);
    __threadfence();
    if (atomicAdd(done, 1u) == 255u) {       // last of 256 blocks
      __threadfence();
      out[4194304] = (float)(1.25 * (*(volatile double*)loss_acc) / 4194304.0);
    }
  }
}

// ---------------- launch
extern "C" void kernel_launch(void* const* d_in, const int* in_sizes, int n_in,
                              void* d_out, int out_size, void* d_ws, size_t ws_size,
                              hipStream_t stream) {
  const float* z = (const float*)d_in[0];
  const float* emb = (const float*)d_in[1];
  float* out = (float*)d_out;
  char* ws = (char*)d_ws;
  float* zt = (float*)(ws + WS_ZT);
  ushort* zpk = (ushort*)(ws + WS_ZPK);
  ushort* epk = (ushort*)(ws + WS_EPK);
  float* sumz = (float*)(ws + WS_SUMZ);
  uint* gmax = (uint*)(ws + WS_GMAX);
  u64* best = (u64*)(ws + WS_BEST);
  double* loss_acc = (double*)(ws + WS_LOSS);
  uint* done = (uint*)(ws + WS_LOSS + 8);

  hipMemsetAsync(ws + WS_LOSS, 0, 16, stream);   // loss_acc + done ctr
  prep_z<<<1024, 256, 0, stream>>>(z, zt, zpk);
  prep_e<<<1024, 256, 0, stream>>>(emb, epk);
  zsum_kernel<<<64, 256, 0, stream>>>(z, sumz);
  gemm_screen<<<2048, 256, 0, stream>>>(zpk, epk, gmax);
  select_rescore<<<4096, 256, 0, stream>>>(gmax, zt, emb, sumz, best);
  gather_kernel<<<256, 256, 0, stream>>>(z, emb, best, out, loss_acc, done);
}